// Round 1
// 243.418 us; speedup vs baseline: 1.0053x; 1.0053x over previous
//
#include <hip/hip_runtime.h>

// Problem constants (B=1)
#define L 512
#define CM 256
#define CZ 128
#define NC 128
#define NBINS 65

typedef float  f4 __attribute__((ext_vector_type(4)));
typedef float  f2 __attribute__((ext_vector_type(2)));
typedef int    i4 __attribute__((ext_vector_type(4)));

// Dtype model (settled): fp32 in/out, int32 residue_index.
// Output = msa_rep [1,256,128,512] fp32, then pair_rep [1,128,512,512] fp32.
// absmax 0.0039 = 1 bf16 ulp of ref max (harness ref is bf16-rounded).

// Kernel 1: tiny per-position linears into fp32 workspace (unchanged, ~4 us).
// a2[c,l] = sum_f w_a_w[c,f]*tf[f,l] + w_a_b[c] + w_p_b[c]   (pair biases folded)
// b2[c,l] = sum_f w_b_w[c,f]*tf[f,l] + w_b_b[c]
// m2[c,l] = sum_f w_m_w[c,f]*tf[f,l] + w_m_b[c]
__global__ void pre_kernel(const float* __restrict__ tf,
                           const float* __restrict__ waw,
                           const float* __restrict__ wab,
                           const float* __restrict__ wbw,
                           const float* __restrict__ wbb,
                           const float* __restrict__ wpb,
                           const float* __restrict__ wmw,
                           const float* __restrict__ wmb,
                           float* __restrict__ a2,
                           float* __restrict__ b2,
                           float* __restrict__ m2) {
    int idx = blockIdx.x * 256 + threadIdx.x;  // 0 .. 262143
    if (idx < CZ * L) {
        int c = idx >> 9, l = idx & (L - 1);
        float acc = wab[c] + wpb[c];
        #pragma unroll
        for (int f = 0; f < 20; ++f)
            acc += waw[c * 20 + f] * tf[f * L + l];
        a2[idx] = acc;
    } else if (idx < 2 * CZ * L) {
        int t = idx - CZ * L;
        int c = t >> 9, l = t & (L - 1);
        float acc = wbb[c];
        #pragma unroll
        for (int f = 0; f < 20; ++f)
            acc += wbw[c * 20 + f] * tf[f * L + l];
        b2[t] = acc;
    } else {
        int t = idx - 2 * CZ * L;   // 0 .. CM*L-1
        int c = t >> 9, l = t & (L - 1);
        float acc = wmb[c];
        #pragma unroll
        for (int f = 0; f < 20; ++f)
            acc += wmw[c * 20 + f] * tf[f * L + l];
        m2[t] = acc;
    }
}

// Fused kernel v2: fat blocks to amortize wave prologue latency.
//   pair blocks  [0, 2048):   c = bx>>4, i0 = (bx&15)*32  -> 32 rows (64 KiB out)
//   msa  blocks  [2048, 4096): c = b>>3, k0 = (b&7)*16    -> 16 k   (32 KiB out)
#define PAIR_BLKS 2048
#define MSA_BLKS  2048

__global__ __launch_bounds__(256)
void fused_kernel(const float* __restrict__ a2,
                  const float* __restrict__ b2,
                  const float* __restrict__ wpw,
                  const int* __restrict__ ri,
                  const float* __restrict__ mf,
                  const float* __restrict__ wc,
                  const float* __restrict__ wcb,
                  const float* __restrict__ m2,
                  float* __restrict__ pair_out,
                  float* __restrict__ msa_out) {
    int bx = blockIdx.x;
    int t = threadIdx.x;

    if (bx < PAIR_BLKS) {
        // ---- pair: pair_rep[c,i,j] = a2[c,i] + b2[c,j] + wp[c, bin(ri_i-ri_j)]
        int c  = bx >> 4;
        int i0 = (bx & 15) * 32;

        __shared__ float swp[NBINS];   // wp row for this c
        __shared__ float sa[32];       // a2 segment for rows i0..i0+31
        __shared__ int   sri[32];      // residue_index segment

        if (t < NBINS)             swp[t]       = wpw[c * NBINS + t];
        if (t >= 128 && t < 160)   sa[t - 128]  = a2[c * L + i0 + (t - 128)];
        if (t >= 192 && t < 224)   sri[t - 192] = ri[i0 + (t - 192)];

        int half = t >> 7;             // waves 0,1 -> 0; waves 2,3 -> 1
        int j0   = (t & 127) * 4;

        i4 rj = *reinterpret_cast<const i4*>(&ri[j0]);
        f4 bb = *reinterpret_cast<const f4*>(&b2[c * L + j0]);

        __syncthreads();

        size_t base0 = ((size_t)c * L + (i0 + half)) * L + j0;

        #pragma unroll
        for (int r = 0; r < 16; ++r) {
            int il = r * 2 + half;       // wave-uniform -> LDS broadcast reads
            float ai  = sa[il];
            int   rii = sri[il];

            int d0 = min(max(rii - rj.x, -32), 32) + 32;
            int d1 = min(max(rii - rj.y, -32), 32) + 32;
            int d2 = min(max(rii - rj.z, -32), 32) + 32;
            int d3 = min(max(rii - rj.w, -32), 32) + 32;

            f4 o;
            o.x = ai + bb.x + swp[d0];
            o.y = ai + bb.y + swp[d1];
            o.z = ai + bb.z + swp[d2];
            o.w = ai + bb.w + swp[d3];

            __builtin_nontemporal_store(
                o, reinterpret_cast<f4*>(&pair_out[base0 + (size_t)r * (2 * L)]));
        }
    } else {
        // ---- msa: msa_rep[c,k,l] = sum_f wc[k,c,f]*mf[f,l] + wcb[k,c] + m2[c,l]
        int b  = bx - PAIR_BLKS;       // 0..2047
        int c  = b >> 3;               // 0..255
        int k0 = (b & 7) * 16;         // 0..112
        int l0 = t * 2;

        float mfa[21], mfb[21];
        #pragma unroll
        for (int f = 0; f < 21; ++f) {
            f2 u = *reinterpret_cast<const f2*>(&mf[f * L + l0]);
            mfa[f] = u.x;
            mfb[f] = u.y;
        }
        f2 mm = *reinterpret_cast<const f2*>(&m2[c * L + l0]);

        #pragma unroll 4
        for (int kk = 0; kk < 16; ++kk) {
            int k = k0 + kk;
            const float* w = &wc[((size_t)k * CM + c) * 21];  // block-uniform -> s_load
            float bias = wcb[k * CM + c];
            float acc0 = bias + mm.x;
            float acc1 = bias + mm.y;
            #pragma unroll
            for (int f = 0; f < 21; ++f) {
                float wf = w[f];
                acc0 += wf * mfa[f];
                acc1 += wf * mfb[f];
            }
            f2 o;
            o.x = acc0;
            o.y = acc1;
            __builtin_nontemporal_store(
                o, reinterpret_cast<f2*>(&msa_out[((size_t)(c * NC + k)) * L + l0]));
        }
    }
}

extern "C" void kernel_launch(void* const* d_in, const int* in_sizes, int n_in,
                              void* d_out, int out_size, void* d_ws, size_t ws_size,
                              hipStream_t stream) {
    const float* tf  = (const float*)d_in[0];   // target_feat [1,20,512] f32
    const int*   ri  = (const int*)d_in[1];     // residue_index [1,512] i32
    const float* mf  = (const float*)d_in[2];   // msa_feat [1,21,512] f32
    const float* waw = (const float*)d_in[3];   // [128,20]
    const float* wab = (const float*)d_in[4];   // [128]
    const float* wbw = (const float*)d_in[5];   // [128,20]
    const float* wbb = (const float*)d_in[6];   // [128]
    const float* wpw = (const float*)d_in[7];   // [128,65]
    const float* wpb = (const float*)d_in[8];   // [128]
    const float* wc  = (const float*)d_in[9];   // [128,256,21]
    const float* wcb = (const float*)d_in[10];  // [128,256]
    const float* wmw = (const float*)d_in[11];  // [256,20]
    const float* wmb = (const float*)d_in[12];  // [256]

    float* out = (float*)d_out;
    float* msa_out  = out;                         // 256*128*512 elems
    float* pair_out = out + (size_t)CM * NC * L;   // 128*512*512 elems

    float* a2 = (float*)d_ws;            // CZ*L
    float* b2 = a2 + CZ * L;             // CZ*L
    float* m2 = b2 + CZ * L;             // CM*L

    // 1) precompute a', b', m' (262144 outputs, biases folded)
    pre_kernel<<<dim3((2 * CZ * L + CM * L) / 256), dim3(256), 0, stream>>>(
        tf, waw, wab, wbw, wbb, wpb, wmw, wmb, a2, b2, m2);

    // 2) fused pair + msa (4096 fat blocks, 16 stores/thread)
    fused_kernel<<<dim3(PAIR_BLKS + MSA_BLKS), dim3(256), 0, stream>>>(
        a2, b2, wpw, ri, mf, wc, wcb, m2, pair_out, msa_out);
}